// Round 2
// baseline (1247.518 us; speedup 1.0000x reference)
//
#include <hip/hip_runtime.h>
#include <hip/hip_bf16.h>
#include <math.h>

#define NP   19000      // NUM_PROTEINS
#define ND   1024       // NUM_DRUGS
#define CHN  256        // IN_CH == EMBED
#define ESG  1500000    // E_SG
#define NSG  800000     // N_SG
#define BDD  4096       // B_DD

// ---------------------------------------------------------------- utilities
static __device__ __forceinline__ int lower_bound_dev(const int* __restrict__ arr, int n, int val) {
    int lo = 0, hi = n;
    while (lo < hi) {
        int mid = (lo + hi) >> 1;
        if (arr[mid] < val) lo = mid + 1; else hi = mid;
    }
    return lo;
}

// ---------------------------------------------------------------- degree
__global__ void deg_kernel(const int* __restrict__ dst, int* __restrict__ deg) {
    int e = blockIdx.x * blockDim.x + threadIdx.x;
    if (e < ESG) atomicAdd(&deg[dst[e]], 1);
}

__global__ void dinv_kernel(const int* __restrict__ deg, float* __restrict__ dinv) {
    int i = blockIdx.x * blockDim.x + threadIdx.x;
    if (i < NP) dinv[i] = 1.0f / sqrtf((float)deg[i] + 1.0f);
}

// single-block exclusive scan of degree -> row_ptr, also seeds cursor
__global__ void scan_kernel(const int* __restrict__ deg, int* __restrict__ row_ptr,
                            int* __restrict__ cursor) {
    const int T = 256;
    const int PER = (NP + T - 1) / T;   // 75
    __shared__ int totals[T];
    __shared__ int excl[T + 1];
    int t = threadIdx.x;
    int base = t * PER;
    int local = 0;
    for (int i = 0; i < PER; i++) {
        int idx = base + i;
        if (idx < NP) local += deg[idx];
    }
    totals[t] = local;
    __syncthreads();
    if (t == 0) {
        int r = 0;
        for (int i = 0; i < T; i++) { excl[i] = r; r += totals[i]; }
        excl[T] = r;
    }
    __syncthreads();
    int run = excl[t];
    for (int i = 0; i < PER; i++) {
        int idx = base + i;
        if (idx < NP) {
            row_ptr[idx] = run;
            cursor[idx]  = run;
            run += deg[idx];
        }
    }
    if (t == 0) row_ptr[NP] = excl[T];
}

__global__ void fill_kernel(const int* __restrict__ src, const int* __restrict__ dst,
                            const float* __restrict__ dinv, int* __restrict__ cursor,
                            int* __restrict__ csr_src, float* __restrict__ csr_w) {
    int e = blockIdx.x * blockDim.x + threadIdx.x;
    if (e >= ESG) return;
    int s = src[e], d = dst[e];
    int pos = atomicAdd(&cursor[d], 1);
    csr_src[pos] = s;
    csr_w[pos]   = dinv[s] * dinv[d];
}

// ---------------------------------------------------------------- fp32 GEMM
// C[M,256] = A[M,256] @ B[256,256]; 64x64 tile, 4x4 per thread, 256 threads.
__global__ __launch_bounds__(256) void gemm_kernel(const float* __restrict__ A,
                                                   const float* __restrict__ B,
                                                   float* __restrict__ C, int M) {
    __shared__ float As[16][68];   // transposed: As[k][m]
    __shared__ float Bs[16][68];   // Bs[k][n]
    int tid = threadIdx.x;
    int m0 = blockIdx.x * 64;
    int n0 = blockIdx.y * 64;
    int tx = tid & 15;             // -> n quad
    int ty = tid >> 4;             // -> m quad
    int ar = tid >> 2;             // A load: row within tile (0..63)
    int ak = (tid & 3) << 2;       // A load: k quad (0,4,8,12)
    int bk = tid >> 4;             // B load: k row (0..15)
    int bn = (tid & 15) << 2;      // B load: n quad
    float acc[4][4] = {};
    for (int k0 = 0; k0 < 256; k0 += 16) {
        float4 av = make_float4(0.f, 0.f, 0.f, 0.f);
        int arow = m0 + ar;
        if (arow < M) av = *(const float4*)(A + (size_t)arow * 256 + k0 + ak);
        As[ak + 0][ar] = av.x; As[ak + 1][ar] = av.y;
        As[ak + 2][ar] = av.z; As[ak + 3][ar] = av.w;
        float4 bv = *(const float4*)(B + (size_t)(k0 + bk) * 256 + n0 + bn);
        *(float4*)&Bs[bk][bn] = bv;
        __syncthreads();
#pragma unroll
        for (int kk = 0; kk < 16; kk++) {
            float4 a = *(const float4*)&As[kk][ty << 2];
            float4 b = *(const float4*)&Bs[kk][tx << 2];
            acc[0][0] += a.x * b.x; acc[0][1] += a.x * b.y; acc[0][2] += a.x * b.z; acc[0][3] += a.x * b.w;
            acc[1][0] += a.y * b.x; acc[1][1] += a.y * b.y; acc[1][2] += a.y * b.z; acc[1][3] += a.y * b.w;
            acc[2][0] += a.z * b.x; acc[2][1] += a.z * b.y; acc[2][2] += a.z * b.z; acc[2][3] += a.z * b.w;
            acc[3][0] += a.w * b.x; acc[3][1] += a.w * b.y; acc[3][2] += a.w * b.z; acc[3][3] += a.w * b.w;
        }
        __syncthreads();
    }
#pragma unroll
    for (int i = 0; i < 4; i++) {
        int row = m0 + (ty << 2) + i;
        if (row < M) {
            float4 o = make_float4(acc[i][0], acc[i][1], acc[i][2], acc[i][3]);
            *(float4*)(C + (size_t)row * 256 + n0 + (tx << 2)) = o;
        }
    }
}

// ---------------------------------------------------------------- SpMM, channel-chunked
// grid = (ceil(NP/4), 4); block = 256 (4 waves). Wave w handles row blockIdx.x*4+w,
// channels [blockIdx.y*64, +64). blockIdx.y slowest-varying -> all blocks of one
// 4.86 MB channel-chunk run as a cohort and stay L2-resident per XCD.
__global__ __launch_bounds__(256) void spmm_kernel(const float* __restrict__ hw,
                                                   const int* __restrict__ row_ptr,
                                                   const int* __restrict__ csr_src,
                                                   const float* __restrict__ csr_w,
                                                   const float* __restrict__ dinv,
                                                   const float* __restrict__ bias,
                                                   const float* __restrict__ residual,
                                                   float* __restrict__ out, int do_relu) {
    int wave = threadIdx.x >> 6;
    int lane = threadIdx.x & 63;
    int row  = blockIdx.x * 4 + wave;
    int c0   = blockIdx.y * 64;
    if (row >= NP) return;
    int lo = row_ptr[row], hi = row_ptr[row + 1];
    float acc = 0.f;
    for (int base = lo; base < hi; base += 64) {
        int n = min(64, hi - base);
        int   sv = 0;
        float wv = 0.f;
        if (lane < n) { sv = csr_src[base + lane]; wv = csr_w[base + lane]; }
        // broadcast each staged edge to the whole wave; order matches CSR order
        for (int j = 0; j < n; j++) {
            int   s = __shfl(sv, j, 64);
            float w = __shfl(wv, j, 64);
            acc += w * hw[(size_t)s * 256 + c0 + lane];
        }
    }
    float dv = dinv[row];
    size_t o = (size_t)row * 256 + c0 + lane;
    acc += hw[o] * dv * dv + bias[c0 + lane];
    if (residual) acc += residual[o];
    if (do_relu) acc = fmaxf(acc, 0.f);
    out[o] = acc;
}

// ---------------------------------------------------------------- pooling, channel-chunked
// grid = (ND/4, 4); block = 256 (4 waves). Wave w -> drug blockIdx.x*4+w,
// channels [blockIdx.y*64, +64).
__global__ __launch_bounds__(256) void pool_kernel(const float* __restrict__ h2,
                                                   const int* __restrict__ sg_nodes,
                                                   const int* __restrict__ sg_idx,
                                                   float* __restrict__ drug_emb) {
    int wave = threadIdx.x >> 6;
    int lane = threadIdx.x & 63;
    int d    = blockIdx.x * 4 + wave;
    int c0   = blockIdx.y * 64;
    if (d >= ND) return;
    // all lanes binary-search the same values -> uniform, scalar-cached
    int lo = lower_bound_dev(sg_idx, NSG, d);
    int hi = lower_bound_dev(sg_idx, NSG, d + 1);
    float acc = 0.f;
    for (int base = lo; base < hi; base += 64) {
        int n = min(64, hi - base);
        int nv = 0;
        if (lane < n) nv = sg_nodes[base + lane];
        for (int j = 0; j < n; j++) {
            int s = __shfl(nv, j, 64);
            acc += h2[(size_t)s * 256 + c0 + lane];
        }
    }
    float c = (float)max(hi - lo, 1);
    drug_emb[(size_t)d * 256 + c0 + lane] = acc / c;
}

// ---------------------------------------------------------------- dot head (wave per pair)
__global__ __launch_bounds__(256) void dot_kernel(const float* __restrict__ drug_emb,
                                                  const int* __restrict__ ddb,
                                                  float* __restrict__ out) {
    int wave = threadIdx.x >> 6;
    int lane = threadIdx.x & 63;
    int p = blockIdx.x * 4 + wave;
    if (p >= BDD) return;
    int a = ddb[p];
    int b = ddb[BDD + p];
    const float4* ea = (const float4*)(drug_emb + (size_t)a * 256);
    const float4* eb = (const float4*)(drug_emb + (size_t)b * 256);
    float4 va = ea[lane];
    float4 vb = eb[lane];
    float s = va.x * vb.x + va.y * vb.y + va.z * vb.z + va.w * vb.w;
#pragma unroll
    for (int off = 32; off > 0; off >>= 1) s += __shfl_down(s, off, 64);
    if (lane == 0) out[p] = s;
}

// ---------------------------------------------------------------- launcher
extern "C" void kernel_launch(void* const* d_in, const int* in_sizes, int n_in,
                              void* d_out, int out_size, void* d_ws, size_t ws_size,
                              hipStream_t stream) {
    const float* x        = (const float*)d_in[0];
    const int*   ddb      = (const int*)d_in[1];
    // d_in[2] edge_attr, d_in[3] edge_cell_lines: unused by reference
    const int*   sg_edge  = (const int*)d_in[4];   // [2, ESG]: src then dst
    const int*   sg_nodes = (const int*)d_in[5];
    const int*   sg_idx   = (const int*)d_in[6];
    const float* W1       = (const float*)d_in[7];
    const float* b1       = (const float*)d_in[8];
    const float* W2       = (const float*)d_in[9];
    const float* b2       = (const float*)d_in[10];
    float* out = (float*)d_out;

    char* ws = (char*)d_ws;
    size_t off = 0;
    auto alloc = [&](size_t bytes) -> void* {
        void* p = ws + off;
        off = (off + bytes + 255) & ~(size_t)255;
        return p;
    };
    int*   deg      = (int*)alloc(NP * sizeof(int));
    float* dinv     = (float*)alloc(NP * sizeof(float));
    int*   row_ptr  = (int*)alloc((NP + 1) * sizeof(int));
    int*   cursor   = (int*)alloc(NP * sizeof(int));
    int*   csr_src  = (int*)alloc((size_t)ESG * sizeof(int));
    float* csr_w    = (float*)alloc((size_t)ESG * sizeof(float));
    float* hwbuf    = (float*)alloc((size_t)NP * CHN * sizeof(float));
    float* h1       = (float*)alloc((size_t)NP * CHN * sizeof(float));
    float* h2       = (float*)alloc((size_t)NP * CHN * sizeof(float));
    float* drug_emb = (float*)alloc((size_t)ND * CHN * sizeof(float));

    const int* src = sg_edge;
    const int* dst = sg_edge + ESG;

    hipMemsetAsync(deg, 0, NP * sizeof(int), stream);
    deg_kernel<<<(ESG + 255) / 256, 256, 0, stream>>>(dst, deg);
    dinv_kernel<<<(NP + 255) / 256, 256, 0, stream>>>(deg, dinv);
    scan_kernel<<<1, 256, 0, stream>>>(deg, row_ptr, cursor);
    fill_kernel<<<(ESG + 255) / 256, 256, 0, stream>>>(src, dst, dinv, cursor, csr_src, csr_w);

    dim3 ggrid((NP + 63) / 64, 4);
    dim3 sgrid((NP + 3) / 4, 4);
    // layer 1: hw = x @ W1 ; h1 = relu(agg + hw*self_norm + b1)
    gemm_kernel<<<ggrid, 256, 0, stream>>>(x, W1, hwbuf, NP);
    spmm_kernel<<<sgrid, 256, 0, stream>>>(hwbuf, row_ptr, csr_src, csr_w, dinv, b1,
                                           nullptr, h1, 1);
    // layer 2: hw = h1 @ W2 ; h2 = (agg + hw*self_norm + b2) + h1
    gemm_kernel<<<ggrid, 256, 0, stream>>>(h1, W2, hwbuf, NP);
    spmm_kernel<<<sgrid, 256, 0, stream>>>(hwbuf, row_ptr, csr_src, csr_w, dinv, b2,
                                           h1, h2, 0);
    // scatter-mean pooling into drug embeddings
    dim3 pgrid(ND / 4, 4);
    pool_kernel<<<pgrid, 256, 0, stream>>>(h2, sg_nodes, sg_idx, drug_emb);
    // dot-product head
    dot_kernel<<<(BDD + 3) / 4, 256, 0, stream>>>(drug_emb, ddb, out);
}

// Round 3
// 1104.068 us; speedup vs baseline: 1.1299x; 1.1299x over previous
//
#include <hip/hip_runtime.h>
#include <hip/hip_bf16.h>
#include <math.h>

#define NP   19000      // NUM_PROTEINS
#define ND   1024       // NUM_DRUGS
#define CHN  256        // IN_CH == EMBED
#define ESG  1500000    // E_SG
#define NSG  800000     // N_SG
#define BDD  4096       // B_DD
#define PSPLIT 4        // entry-parallel splits per drug in pooling

// ---------------------------------------------------------------- utilities
static __device__ __forceinline__ int lower_bound_dev(const int* __restrict__ arr, int n, int val) {
    int lo = 0, hi = n;
    while (lo < hi) {
        int mid = (lo + hi) >> 1;
        if (arr[mid] < val) lo = mid + 1; else hi = mid;
    }
    return lo;
}

// ---------------------------------------------------------------- degree
__global__ void deg_kernel(const int* __restrict__ dst, int* __restrict__ deg) {
    int e = blockIdx.x * blockDim.x + threadIdx.x;
    if (e < ESG) atomicAdd(&deg[dst[e]], 1);
}

__global__ void dinv_kernel(const int* __restrict__ deg, float* __restrict__ dinv) {
    int i = blockIdx.x * blockDim.x + threadIdx.x;
    if (i < NP) dinv[i] = 1.0f / sqrtf((float)deg[i] + 1.0f);
}

// single-block exclusive scan of degree -> row_ptr, also seeds cursor
__global__ void scan_kernel(const int* __restrict__ deg, int* __restrict__ row_ptr,
                            int* __restrict__ cursor) {
    const int T = 256;
    const int PER = (NP + T - 1) / T;   // 75
    __shared__ int totals[T];
    __shared__ int excl[T + 1];
    int t = threadIdx.x;
    int base = t * PER;
    int local = 0;
    for (int i = 0; i < PER; i++) {
        int idx = base + i;
        if (idx < NP) local += deg[idx];
    }
    totals[t] = local;
    __syncthreads();
    if (t == 0) {
        int r = 0;
        for (int i = 0; i < T; i++) { excl[i] = r; r += totals[i]; }
        excl[T] = r;
    }
    __syncthreads();
    int run = excl[t];
    for (int i = 0; i < PER; i++) {
        int idx = base + i;
        if (idx < NP) {
            row_ptr[idx] = run;
            cursor[idx]  = run;
            run += deg[idx];
        }
    }
    if (t == 0) row_ptr[NP] = excl[T];
}

__global__ void fill_kernel(const int* __restrict__ src, const int* __restrict__ dst,
                            const float* __restrict__ dinv, int* __restrict__ cursor,
                            int* __restrict__ csr_src, float* __restrict__ csr_w) {
    int e = blockIdx.x * blockDim.x + threadIdx.x;
    if (e >= ESG) return;
    int s = src[e], d = dst[e];
    int pos = atomicAdd(&cursor[d], 1);
    csr_src[pos] = s;
    csr_w[pos]   = dinv[s] * dinv[d];
}

// ---------------------------------------------------------------- fp32 GEMM
// C[M,256] = A[M,256] @ B[256,256]; 64x64 tile, 4x4 per thread, 256 threads.
__global__ __launch_bounds__(256) void gemm_kernel(const float* __restrict__ A,
                                                   const float* __restrict__ B,
                                                   float* __restrict__ C, int M) {
    __shared__ float As[16][68];   // transposed: As[k][m]
    __shared__ float Bs[16][68];   // Bs[k][n]
    int tid = threadIdx.x;
    int m0 = blockIdx.x * 64;
    int n0 = blockIdx.y * 64;
    int tx = tid & 15;             // -> n quad
    int ty = tid >> 4;             // -> m quad
    int ar = tid >> 2;             // A load: row within tile (0..63)
    int ak = (tid & 3) << 2;       // A load: k quad (0,4,8,12)
    int bk = tid >> 4;             // B load: k row (0..15)
    int bn = (tid & 15) << 2;      // B load: n quad
    float acc[4][4] = {};
    for (int k0 = 0; k0 < 256; k0 += 16) {
        float4 av = make_float4(0.f, 0.f, 0.f, 0.f);
        int arow = m0 + ar;
        if (arow < M) av = *(const float4*)(A + (size_t)arow * 256 + k0 + ak);
        As[ak + 0][ar] = av.x; As[ak + 1][ar] = av.y;
        As[ak + 2][ar] = av.z; As[ak + 3][ar] = av.w;
        float4 bv = *(const float4*)(B + (size_t)(k0 + bk) * 256 + n0 + bn);
        *(float4*)&Bs[bk][bn] = bv;
        __syncthreads();
#pragma unroll
        for (int kk = 0; kk < 16; kk++) {
            float4 a = *(const float4*)&As[kk][ty << 2];
            float4 b = *(const float4*)&Bs[kk][tx << 2];
            acc[0][0] += a.x * b.x; acc[0][1] += a.x * b.y; acc[0][2] += a.x * b.z; acc[0][3] += a.x * b.w;
            acc[1][0] += a.y * b.x; acc[1][1] += a.y * b.y; acc[1][2] += a.y * b.z; acc[1][3] += a.y * b.w;
            acc[2][0] += a.z * b.x; acc[2][1] += a.z * b.y; acc[2][2] += a.z * b.z; acc[2][3] += a.z * b.w;
            acc[3][0] += a.w * b.x; acc[3][1] += a.w * b.y; acc[3][2] += a.w * b.z; acc[3][3] += a.w * b.w;
        }
        __syncthreads();
    }
#pragma unroll
    for (int i = 0; i < 4; i++) {
        int row = m0 + (ty << 2) + i;
        if (row < M) {
            float4 o = make_float4(acc[i][0], acc[i][1], acc[i][2], acc[i][3]);
            *(float4*)(C + (size_t)row * 256 + n0 + (tx << 2)) = o;
        }
    }
}

// ---------------------------------------------------------------- SpMM, sequential channel-chunk
// One LAUNCH per 64-channel chunk (c0 = 0,64,128,192); the chunk's gather set
// (19000x64 fp32 = 4.86 MB) fits a per-XCD 4 MiB L2, so gathers hit L2.
// Block = 256 threads = 4 waves over ONE dst row: cooperative 256-edge LDS
// stage, wave w consumes staged edges [64w, 64w+64) x 64 channels (unrolled
// independent gathers), cross-wave LDS reduce, epilogue by wave 0.
__global__ __launch_bounds__(256) void spmm_chunk_kernel(const float* __restrict__ hw,
                                                         const int* __restrict__ row_ptr,
                                                         const int* __restrict__ csr_src,
                                                         const float* __restrict__ csr_w,
                                                         const float* __restrict__ dinv,
                                                         const float* __restrict__ bias,
                                                         const float* __restrict__ residual,
                                                         float* __restrict__ out,
                                                         int do_relu, int c0) {
    int row = blockIdx.x;
    int tid = threadIdx.x;
    int ch  = tid & 63;
    int sub = tid >> 6;
    __shared__ int   s_src[256];
    __shared__ float s_w[256];
    __shared__ float s_red[4][64];
    int lo = row_ptr[row], hi = row_ptr[row + 1];
    float acc = 0.f;
    for (int base = lo; base < hi; base += 256) {   // trip count uniform per block
        int i = base + tid;
        if (i < hi) { s_src[tid] = csr_src[i]; s_w[tid] = csr_w[i]; }
        __syncthreads();
        int cnt = min(256, hi - base);
        int je = min(sub * 64 + 64, cnt);
#pragma unroll 4
        for (int j = sub * 64; j < je; j++) {
            acc += s_w[j] * hw[(size_t)s_src[j] * 256 + c0 + ch];
        }
        __syncthreads();
    }
    s_red[sub][ch] = acc;
    __syncthreads();
    if (sub == 0) {
        float r = s_red[0][ch] + s_red[1][ch] + s_red[2][ch] + s_red[3][ch];
        float dv = dinv[row];
        size_t o = (size_t)row * 256 + c0 + ch;
        r += hw[o] * dv * dv + bias[c0 + ch];
        if (residual) r += residual[o];
        if (do_relu) r = fmaxf(r, 0.f);
        out[o] = r;
    }
}

// ---------------------------------------------------------------- pooling, sequential channel-chunk
// One launch per 64-channel chunk; grid = (ND, PSPLIT): block (d, part) sums
// the part-th quarter of drug d's node list over channels [c0, c0+64), and
// atomically accumulates the partial into drug_emb. finalize divides by count.
__global__ __launch_bounds__(256) void pool_chunk_kernel(const float* __restrict__ h2,
                                                         const int* __restrict__ sg_nodes,
                                                         const int* __restrict__ sg_idx,
                                                         float* __restrict__ drug_emb,
                                                         int c0) {
    int d    = blockIdx.x;
    int part = blockIdx.y;
    int tid  = threadIdx.x;
    int ch   = tid & 63;
    int sub  = tid >> 6;
    __shared__ int   s_nodes[256];
    __shared__ float s_red[4][64];
    int lo0 = lower_bound_dev(sg_idx, NSG, d);       // uniform across block
    int hi0 = lower_bound_dev(sg_idx, NSG, d + 1);
    int len = hi0 - lo0;
    int lo = lo0 + (int)(((long long)len * part) / PSPLIT);
    int hi = lo0 + (int)(((long long)len * (part + 1)) / PSPLIT);
    float acc = 0.f;
    for (int base = lo; base < hi; base += 256) {
        int i = base + tid;
        if (i < hi) s_nodes[tid] = sg_nodes[i];
        __syncthreads();
        int cnt = min(256, hi - base);
        int je = min(sub * 64 + 64, cnt);
#pragma unroll 4
        for (int j = sub * 64; j < je; j++) {
            acc += h2[(size_t)s_nodes[j] * 256 + c0 + ch];
        }
        __syncthreads();
    }
    s_red[sub][ch] = acc;
    __syncthreads();
    if (sub == 0) {
        float r = s_red[0][ch] + s_red[1][ch] + s_red[2][ch] + s_red[3][ch];
        atomicAdd(&drug_emb[(size_t)d * 256 + c0 + ch], r);
    }
}

__global__ __launch_bounds__(256) void pool_fin_kernel(const int* __restrict__ sg_idx,
                                                       float* __restrict__ drug_emb) {
    int d  = blockIdx.x;
    int ch = threadIdx.x;
    int lo = lower_bound_dev(sg_idx, NSG, d);
    int hi = lower_bound_dev(sg_idx, NSG, d + 1);
    float c = (float)max(hi - lo, 1);
    drug_emb[(size_t)d * 256 + ch] /= c;
}

// ---------------------------------------------------------------- dot head (wave per pair)
__global__ __launch_bounds__(256) void dot_kernel(const float* __restrict__ drug_emb,
                                                  const int* __restrict__ ddb,
                                                  float* __restrict__ out) {
    int wave = threadIdx.x >> 6;
    int lane = threadIdx.x & 63;
    int p = blockIdx.x * 4 + wave;
    if (p >= BDD) return;
    int a = ddb[p];
    int b = ddb[BDD + p];
    const float4* ea = (const float4*)(drug_emb + (size_t)a * 256);
    const float4* eb = (const float4*)(drug_emb + (size_t)b * 256);
    float4 va = ea[lane];
    float4 vb = eb[lane];
    float s = va.x * vb.x + va.y * vb.y + va.z * vb.z + va.w * vb.w;
#pragma unroll
    for (int off = 32; off > 0; off >>= 1) s += __shfl_down(s, off, 64);
    if (lane == 0) out[p] = s;
}

// ---------------------------------------------------------------- launcher
extern "C" void kernel_launch(void* const* d_in, const int* in_sizes, int n_in,
                              void* d_out, int out_size, void* d_ws, size_t ws_size,
                              hipStream_t stream) {
    const float* x        = (const float*)d_in[0];
    const int*   ddb      = (const int*)d_in[1];
    // d_in[2] edge_attr, d_in[3] edge_cell_lines: unused by reference
    const int*   sg_edge  = (const int*)d_in[4];   // [2, ESG]: src then dst
    const int*   sg_nodes = (const int*)d_in[5];
    const int*   sg_idx   = (const int*)d_in[6];
    const float* W1       = (const float*)d_in[7];
    const float* b1       = (const float*)d_in[8];
    const float* W2       = (const float*)d_in[9];
    const float* b2       = (const float*)d_in[10];
    float* out = (float*)d_out;

    char* ws = (char*)d_ws;
    size_t off = 0;
    auto alloc = [&](size_t bytes) -> void* {
        void* p = ws + off;
        off = (off + bytes + 255) & ~(size_t)255;
        return p;
    };
    int*   deg      = (int*)alloc(NP * sizeof(int));
    float* dinv     = (float*)alloc(NP * sizeof(float));
    int*   row_ptr  = (int*)alloc((NP + 1) * sizeof(int));
    int*   cursor   = (int*)alloc(NP * sizeof(int));
    int*   csr_src  = (int*)alloc((size_t)ESG * sizeof(int));
    float* csr_w    = (float*)alloc((size_t)ESG * sizeof(float));
    float* hwbuf    = (float*)alloc((size_t)NP * CHN * sizeof(float));
    float* h1       = (float*)alloc((size_t)NP * CHN * sizeof(float));
    float* h2       = (float*)alloc((size_t)NP * CHN * sizeof(float));
    float* drug_emb = (float*)alloc((size_t)ND * CHN * sizeof(float));

    const int* src = sg_edge;
    const int* dst = sg_edge + ESG;

    hipMemsetAsync(deg, 0, NP * sizeof(int), stream);
    hipMemsetAsync(drug_emb, 0, (size_t)ND * CHN * sizeof(float), stream);
    deg_kernel<<<(ESG + 255) / 256, 256, 0, stream>>>(dst, deg);
    dinv_kernel<<<(NP + 255) / 256, 256, 0, stream>>>(deg, dinv);
    scan_kernel<<<1, 256, 0, stream>>>(deg, row_ptr, cursor);
    fill_kernel<<<(ESG + 255) / 256, 256, 0, stream>>>(src, dst, dinv, cursor, csr_src, csr_w);

    dim3 ggrid((NP + 63) / 64, 4);
    // layer 1: hw = x @ W1 ; h1 = relu(agg + hw*self_norm + b1)
    gemm_kernel<<<ggrid, 256, 0, stream>>>(x, W1, hwbuf, NP);
    for (int c0 = 0; c0 < CHN; c0 += 64)
        spmm_chunk_kernel<<<NP, 256, 0, stream>>>(hwbuf, row_ptr, csr_src, csr_w, dinv,
                                                  b1, nullptr, h1, 1, c0);
    // layer 2: hw = h1 @ W2 ; h2 = (agg + hw*self_norm + b2) + h1
    gemm_kernel<<<ggrid, 256, 0, stream>>>(h1, W2, hwbuf, NP);
    for (int c0 = 0; c0 < CHN; c0 += 64)
        spmm_chunk_kernel<<<NP, 256, 0, stream>>>(hwbuf, row_ptr, csr_src, csr_w, dinv,
                                                  b2, h1, h2, 0, c0);
    // scatter-mean pooling into drug embeddings (chunked, entry-split, atomic)
    dim3 pgrid(ND, PSPLIT);
    for (int c0 = 0; c0 < CHN; c0 += 64)
        pool_chunk_kernel<<<pgrid, 256, 0, stream>>>(h2, sg_nodes, sg_idx, drug_emb, c0);
    pool_fin_kernel<<<ND, 256, 0, stream>>>(sg_idx, drug_emb);
    // dot-product head
    dot_kernel<<<(BDD + 3) / 4, 256, 0, stream>>>(drug_emb, ddb, out);
}

// Round 4
// 1091.516 us; speedup vs baseline: 1.1429x; 1.0115x over previous
//
#include <hip/hip_runtime.h>
#include <hip/hip_bf16.h>
#include <math.h>

#define NP   19000      // NUM_PROTEINS
#define ND   1024       // NUM_DRUGS
#define CHN  256        // IN_CH == EMBED
#define ESG  1500000    // E_SG
#define NSG  800000     // N_SG
#define BDD  4096       // B_DD
#define PSPLIT 4        // entry-parallel splits per drug in pooling
#define CCH  32         // channel chunk width (19000*32*4B = 2.43 MB < 4 MiB L2)

#define GEMM_BX   ((NP + 63) / 64)       // 297
#define GEMM_BLK  (GEMM_BX * 4)          // 1188
#define FILL_BLK  ((ESG + 255) / 256)    // 5860

// ---------------------------------------------------------------- utilities
static __device__ __forceinline__ int lower_bound_dev(const int* __restrict__ arr, int n, int val) {
    int lo = 0, hi = n;
    while (lo < hi) {
        int mid = (lo + hi) >> 1;
        if (arr[mid] < val) lo = mid + 1; else hi = mid;
    }
    return lo;
}

// ---------------------------------------------------------------- degree
__global__ void deg_kernel(const int* __restrict__ dst, int* __restrict__ deg) {
    int e = blockIdx.x * blockDim.x + threadIdx.x;
    if (e < ESG) atomicAdd(&deg[dst[e]], 1);
}

__global__ void dinv_kernel(const int* __restrict__ deg, float* __restrict__ dinv) {
    int i = blockIdx.x * blockDim.x + threadIdx.x;
    if (i < NP) dinv[i] = 1.0f / sqrtf((float)deg[i] + 1.0f);
}

// single-block exclusive scan of degree -> row_ptr, also seeds cursor
__global__ void scan_kernel(const int* __restrict__ deg, int* __restrict__ row_ptr,
                            int* __restrict__ cursor) {
    const int T = 256;
    const int PER = (NP + T - 1) / T;   // 75
    __shared__ int totals[T];
    __shared__ int excl[T + 1];
    int t = threadIdx.x;
    int base = t * PER;
    int local = 0;
    for (int i = 0; i < PER; i++) {
        int idx = base + i;
        if (idx < NP) local += deg[idx];
    }
    totals[t] = local;
    __syncthreads();
    if (t == 0) {
        int r = 0;
        for (int i = 0; i < T; i++) { excl[i] = r; r += totals[i]; }
        excl[T] = r;
    }
    __syncthreads();
    int run = excl[t];
    for (int i = 0; i < PER; i++) {
        int idx = base + i;
        if (idx < NP) {
            row_ptr[idx] = run;
            cursor[idx]  = run;
            run += deg[idx];
        }
    }
    if (t == 0) row_ptr[NP] = excl[T];
}

// ---------------------------------------------------------------- device bodies
// GEMM body: C[M,256] = A[M,256] @ B[256,256]; 64x64 tile, 4x4/thread.
static __device__ __forceinline__ void gemm_body(const float* __restrict__ A,
                                                 const float* __restrict__ B,
                                                 float* __restrict__ C, int M,
                                                 int bx, int by) {
    __shared__ float As[16][68];   // transposed: As[k][m]
    __shared__ float Bs[16][68];   // Bs[k][n]
    int tid = threadIdx.x;
    int m0 = bx * 64;
    int n0 = by * 64;
    int tx = tid & 15;
    int ty = tid >> 4;
    int ar = tid >> 2;
    int ak = (tid & 3) << 2;
    int bk = tid >> 4;
    int bn = (tid & 15) << 2;
    float acc[4][4] = {};
    for (int k0 = 0; k0 < 256; k0 += 16) {
        float4 av = make_float4(0.f, 0.f, 0.f, 0.f);
        int arow = m0 + ar;
        if (arow < M) av = *(const float4*)(A + (size_t)arow * 256 + k0 + ak);
        As[ak + 0][ar] = av.x; As[ak + 1][ar] = av.y;
        As[ak + 2][ar] = av.z; As[ak + 3][ar] = av.w;
        float4 bv = *(const float4*)(B + (size_t)(k0 + bk) * 256 + n0 + bn);
        *(float4*)&Bs[bk][bn] = bv;
        __syncthreads();
#pragma unroll
        for (int kk = 0; kk < 16; kk++) {
            float4 a = *(const float4*)&As[kk][ty << 2];
            float4 b = *(const float4*)&Bs[kk][tx << 2];
            acc[0][0] += a.x * b.x; acc[0][1] += a.x * b.y; acc[0][2] += a.x * b.z; acc[0][3] += a.x * b.w;
            acc[1][0] += a.y * b.x; acc[1][1] += a.y * b.y; acc[1][2] += a.y * b.z; acc[1][3] += a.y * b.w;
            acc[2][0] += a.z * b.x; acc[2][1] += a.z * b.y; acc[2][2] += a.z * b.z; acc[2][3] += a.z * b.w;
            acc[3][0] += a.w * b.x; acc[3][1] += a.w * b.y; acc[3][2] += a.w * b.z; acc[3][3] += a.w * b.w;
        }
        __syncthreads();
    }
#pragma unroll
    for (int i = 0; i < 4; i++) {
        int row = m0 + (ty << 2) + i;
        if (row < M) {
            float4 o = make_float4(acc[i][0], acc[i][1], acc[i][2], acc[i][3]);
            *(float4*)(C + (size_t)row * 256 + n0 + (tx << 2)) = o;
        }
    }
}

// ---------------------------------------------------------------- plain gemm kernel (layer 2)
__global__ __launch_bounds__(256) void gemm_kernel(const float* __restrict__ A,
                                                   const float* __restrict__ B,
                                                   float* __restrict__ C, int M) {
    gemm_body(A, B, C, M, blockIdx.x, blockIdx.y);
}

// ---------------------------------------------------------------- fused fill + gemm1
// gemm blocks first (compute-bound), fill blocks after (write/latency-bound):
// they co-schedule on complementary pipes. CSR record = int2{src, bits(w)} ->
// ONE 8B scattered store per edge (half the dirty-line traffic of two 4B).
__global__ __launch_bounds__(256) void fill_gemm_kernel(const int* __restrict__ src,
                                                        const int* __restrict__ dst,
                                                        const float* __restrict__ dinv,
                                                        int* __restrict__ cursor,
                                                        int2* __restrict__ csr,
                                                        const float* __restrict__ A,
                                                        const float* __restrict__ B,
                                                        float* __restrict__ C) {
    if (blockIdx.x < GEMM_BLK) {
        gemm_body(A, B, C, NP, blockIdx.x >> 2, blockIdx.x & 3);
        return;
    }
    int e = (blockIdx.x - GEMM_BLK) * 256 + threadIdx.x;
    if (e >= ESG) return;
    int s = src[e], d = dst[e];
    int pos = atomicAdd(&cursor[d], 1);
    int2 rec;
    rec.x = s;
    rec.y = __float_as_int(dinv[s] * dinv[d]);
    csr[pos] = rec;
}

// ---------------------------------------------------------------- SpMM, 32-channel chunk
// One launch per CCH-channel chunk; the chunk's gather set (2.43 MB) is
// L2-resident per XCD. Block = one dst row, 256 threads = 8 subgroups of 32:
// cooperative 256-edge LDS stage, sub s consumes edges [32s,32s+32) over the
// 32 chunk channels (unrolled independent gathers), LDS reduce, epilogue.
__global__ __launch_bounds__(256) void spmm_chunk_kernel(const float* __restrict__ hw,
                                                         const int* __restrict__ row_ptr,
                                                         const int2* __restrict__ csr,
                                                         const float* __restrict__ dinv,
                                                         const float* __restrict__ bias,
                                                         const float* __restrict__ residual,
                                                         float* __restrict__ out,
                                                         int do_relu, int c0) {
    int row = blockIdx.x;
    int tid = threadIdx.x;
    int ch  = tid & 31;
    int sub = tid >> 5;
    __shared__ int2  s_rec[256];
    __shared__ float s_red[8][32];
    int lo = row_ptr[row], hi = row_ptr[row + 1];
    float acc = 0.f;
    for (int base = lo; base < hi; base += 256) {   // trip count uniform per block
        int i = base + tid;
        if (i < hi) s_rec[tid] = csr[i];
        __syncthreads();
        int cnt = min(256, hi - base);
        int js = sub * 32;
        int je = min(js + 32, cnt);
#pragma unroll 4
        for (int j = js; j < je; j++) {
            int2 r = s_rec[j];
            acc += __int_as_float(r.y) * hw[(size_t)r.x * 256 + c0 + ch];
        }
        __syncthreads();
    }
    s_red[sub][ch] = acc;
    __syncthreads();
    if (sub == 0) {
        float r = 0.f;
#pragma unroll
        for (int k = 0; k < 8; k++) r += s_red[k][ch];
        float dv = dinv[row];
        size_t o = (size_t)row * 256 + c0 + ch;
        r += hw[o] * dv * dv + bias[c0 + ch];
        if (residual) r += residual[o];
        if (do_relu) r = fmaxf(r, 0.f);
        out[o] = r;
    }
}

// ---------------------------------------------------------------- pooling, 32-channel chunk
// grid = (ND, PSPLIT): block (d, part) sums the part-th quarter of drug d's
// node list over channels [c0,c0+32), atomically accumulating partials.
__global__ __launch_bounds__(256) void pool_chunk_kernel(const float* __restrict__ h2,
                                                         const int* __restrict__ sg_nodes,
                                                         const int* __restrict__ sg_idx,
                                                         float* __restrict__ drug_emb,
                                                         int c0) {
    int d    = blockIdx.x;
    int part = blockIdx.y;
    int tid  = threadIdx.x;
    int ch   = tid & 31;
    int sub  = tid >> 5;
    __shared__ int   s_nodes[256];
    __shared__ float s_red[8][32];
    int lo0 = lower_bound_dev(sg_idx, NSG, d);       // uniform across block
    int hi0 = lower_bound_dev(sg_idx, NSG, d + 1);
    int len = hi0 - lo0;
    int lo = lo0 + (int)(((long long)len * part) / PSPLIT);
    int hi = lo0 + (int)(((long long)len * (part + 1)) / PSPLIT);
    float acc = 0.f;
    for (int base = lo; base < hi; base += 256) {
        int i = base + tid;
        if (i < hi) s_nodes[tid] = sg_nodes[i];
        __syncthreads();
        int cnt = min(256, hi - base);
        int js = sub * 32;
        int je = min(js + 32, cnt);
#pragma unroll 4
        for (int j = js; j < je; j++) {
            acc += h2[(size_t)s_nodes[j] * 256 + c0 + ch];
        }
        __syncthreads();
    }
    s_red[sub][ch] = acc;
    __syncthreads();
    if (sub == 0) {
        float r = 0.f;
#pragma unroll
        for (int k = 0; k < 8; k++) r += s_red[k][ch];
        atomicAdd(&drug_emb[(size_t)d * 256 + c0 + ch], r);
    }
}

__global__ __launch_bounds__(256) void pool_fin_kernel(const int* __restrict__ sg_idx,
                                                       float* __restrict__ drug_emb) {
    int d  = blockIdx.x;
    int ch = threadIdx.x;
    int lo = lower_bound_dev(sg_idx, NSG, d);
    int hi = lower_bound_dev(sg_idx, NSG, d + 1);
    float c = (float)max(hi - lo, 1);
    drug_emb[(size_t)d * 256 + ch] /= c;
}

// ---------------------------------------------------------------- dot head (wave per pair)
__global__ __launch_bounds__(256) void dot_kernel(const float* __restrict__ drug_emb,
                                                  const int* __restrict__ ddb,
                                                  float* __restrict__ out) {
    int wave = threadIdx.x >> 6;
    int lane = threadIdx.x & 63;
    int p = blockIdx.x * 4 + wave;
    if (p >= BDD) return;
    int a = ddb[p];
    int b = ddb[BDD + p];
    const float4* ea = (const float4*)(drug_emb + (size_t)a * 256);
    const float4* eb = (const float4*)(drug_emb + (size_t)b * 256);
    float4 va = ea[lane];
    float4 vb = eb[lane];
    float s = va.x * vb.x + va.y * vb.y + va.z * vb.z + va.w * vb.w;
#pragma unroll
    for (int off = 32; off > 0; off >>= 1) s += __shfl_down(s, off, 64);
    if (lane == 0) out[p] = s;
}

// ---------------------------------------------------------------- launcher
extern "C" void kernel_launch(void* const* d_in, const int* in_sizes, int n_in,
                              void* d_out, int out_size, void* d_ws, size_t ws_size,
                              hipStream_t stream) {
    const float* x        = (const float*)d_in[0];
    const int*   ddb      = (const int*)d_in[1];
    // d_in[2] edge_attr, d_in[3] edge_cell_lines: unused by reference
    const int*   sg_edge  = (const int*)d_in[4];   // [2, ESG]: src then dst
    const int*   sg_nodes = (const int*)d_in[5];
    const int*   sg_idx   = (const int*)d_in[6];
    const float* W1       = (const float*)d_in[7];
    const float* b1       = (const float*)d_in[8];
    const float* W2       = (const float*)d_in[9];
    const float* b2       = (const float*)d_in[10];
    float* out = (float*)d_out;

    char* ws = (char*)d_ws;
    size_t off = 0;
    auto alloc = [&](size_t bytes) -> void* {
        void* p = ws + off;
        off = (off + bytes + 255) & ~(size_t)255;
        return p;
    };
    int*   deg      = (int*)alloc(NP * sizeof(int));
    float* dinv     = (float*)alloc(NP * sizeof(float));
    int*   row_ptr  = (int*)alloc((NP + 1) * sizeof(int));
    int*   cursor   = (int*)alloc(NP * sizeof(int));
    int2*  csr      = (int2*)alloc((size_t)ESG * sizeof(int2));
    float* hwbuf    = (float*)alloc((size_t)NP * CHN * sizeof(float));
    float* h1       = (float*)alloc((size_t)NP * CHN * sizeof(float));
    float* h2       = (float*)alloc((size_t)NP * CHN * sizeof(float));
    float* drug_emb = (float*)alloc((size_t)ND * CHN * sizeof(float));

    const int* src = sg_edge;
    const int* dst = sg_edge + ESG;

    hipMemsetAsync(deg, 0, NP * sizeof(int), stream);
    hipMemsetAsync(drug_emb, 0, (size_t)ND * CHN * sizeof(float), stream);
    deg_kernel<<<(ESG + 255) / 256, 256, 0, stream>>>(dst, deg);
    dinv_kernel<<<(NP + 255) / 256, 256, 0, stream>>>(deg, dinv);
    scan_kernel<<<1, 256, 0, stream>>>(deg, row_ptr, cursor);

    // fused: CSR fill + gemm1 (hw = x @ W1) — independent work, one launch
    fill_gemm_kernel<<<GEMM_BLK + FILL_BLK, 256, 0, stream>>>(src, dst, dinv, cursor,
                                                              csr, x, W1, hwbuf);
    // layer 1: h1 = relu(agg + hw*self_norm + b1), 32-ch chunks
    for (int c0 = 0; c0 < CHN; c0 += CCH)
        spmm_chunk_kernel<<<NP, 256, 0, stream>>>(hwbuf, row_ptr, csr, dinv,
                                                  b1, nullptr, h1, 1, c0);
    // layer 2: hw = h1 @ W2 ; h2 = (agg + hw*self_norm + b2) + h1
    gemm_kernel<<<dim3(GEMM_BX, 4), 256, 0, stream>>>(h1, W2, hwbuf, NP);
    for (int c0 = 0; c0 < CHN; c0 += CCH)
        spmm_chunk_kernel<<<NP, 256, 0, stream>>>(hwbuf, row_ptr, csr, dinv,
                                                  b2, h1, h2, 0, c0);
    // scatter-mean pooling (chunked, entry-split, atomic)
    dim3 pgrid(ND, PSPLIT);
    for (int c0 = 0; c0 < CHN; c0 += CCH)
        pool_chunk_kernel<<<pgrid, 256, 0, stream>>>(h2, sg_nodes, sg_idx, drug_emb, c0);
    pool_fin_kernel<<<ND, 256, 0, stream>>>(sg_idx, drug_emb);
    // dot-product head
    dot_kernel<<<(BDD + 3) / 4, 256, 0, stream>>>(drug_emb, ddb, out);
}

// Round 5
// 627.302 us; speedup vs baseline: 1.9887x; 1.7400x over previous
//
#include <hip/hip_runtime.h>
#include <hip/hip_bf16.h>
#include <math.h>

#define NP   19000      // NUM_PROTEINS
#define ND   1024       // NUM_DRUGS
#define CHN  256        // IN_CH == EMBED
#define ESG  1500000    // E_SG
#define NSG  800000     // N_SG
#define BDD  4096       // B_DD
#define PSPLIT 2        // entry-parallel splits per drug in pooling

#define GEMM_BX   ((NP + 63) / 64)       // 297
#define GEMM_BLK  (GEMM_BX * 4)          // 1188
#define FILL_BLK  ((ESG + 255) / 256)    // 5860

// ---------------------------------------------------------------- bf16 helpers (raw ushort)
static __device__ __forceinline__ unsigned short f2bf(float f) {
    unsigned u = __float_as_uint(f);
    u = u + 0x7fffu + ((u >> 16) & 1u);        // round-to-nearest-even
    return (unsigned short)(u >> 16);
}
static __device__ __forceinline__ float bf2f(unsigned short h) {
    return __uint_as_float((unsigned)h << 16);
}

// ---------------------------------------------------------------- utilities
static __device__ __forceinline__ int lower_bound_dev(const int* __restrict__ arr, int n, int val) {
    int lo = 0, hi = n;
    while (lo < hi) {
        int mid = (lo + hi) >> 1;
        if (arr[mid] < val) lo = mid + 1; else hi = mid;
    }
    return lo;
}

// ---------------------------------------------------------------- degree
__global__ void deg_kernel(const int* __restrict__ dst, int* __restrict__ deg) {
    int e = blockIdx.x * blockDim.x + threadIdx.x;
    if (e < ESG) atomicAdd(&deg[dst[e]], 1);
}

__global__ void dinv_kernel(const int* __restrict__ deg, float* __restrict__ dinv) {
    int i = blockIdx.x * blockDim.x + threadIdx.x;
    if (i < NP) dinv[i] = 1.0f / sqrtf((float)deg[i] + 1.0f);
}

// single-block exclusive scan of degree -> row_ptr, also seeds cursor
__global__ void scan_kernel(const int* __restrict__ deg, int* __restrict__ row_ptr,
                            int* __restrict__ cursor) {
    const int T = 256;
    const int PER = (NP + T - 1) / T;   // 75
    __shared__ int totals[T];
    __shared__ int excl[T + 1];
    int t = threadIdx.x;
    int base = t * PER;
    int local = 0;
    for (int i = 0; i < PER; i++) {
        int idx = base + i;
        if (idx < NP) local += deg[idx];
    }
    totals[t] = local;
    __syncthreads();
    if (t == 0) {
        int r = 0;
        for (int i = 0; i < T; i++) { excl[i] = r; r += totals[i]; }
        excl[T] = r;
    }
    __syncthreads();
    int run = excl[t];
    for (int i = 0; i < PER; i++) {
        int idx = base + i;
        if (idx < NP) {
            row_ptr[idx] = run;
            cursor[idx]  = run;
            run += deg[idx];
        }
    }
    if (t == 0) row_ptr[NP] = excl[T];
}

// ---------------------------------------------------------------- GEMM body
// C[M,256] = A[M,256] @ B[256,256]; 64x64 tile, 4x4/thread; dual fp32+bf16 out.
static __device__ __forceinline__ void gemm_body(const float* __restrict__ A,
                                                 const float* __restrict__ B,
                                                 float* __restrict__ C,
                                                 unsigned short* __restrict__ Cb,
                                                 int M, int bx, int by) {
    __shared__ float As[16][68];   // transposed: As[k][m]
    __shared__ float Bs[16][68];   // Bs[k][n]
    int tid = threadIdx.x;
    int m0 = bx * 64;
    int n0 = by * 64;
    int tx = tid & 15;
    int ty = tid >> 4;
    int ar = tid >> 2;
    int ak = (tid & 3) << 2;
    int bk = tid >> 4;
    int bn = (tid & 15) << 2;
    float acc[4][4] = {};
    for (int k0 = 0; k0 < 256; k0 += 16) {
        float4 av = make_float4(0.f, 0.f, 0.f, 0.f);
        int arow = m0 + ar;
        if (arow < M) av = *(const float4*)(A + (size_t)arow * 256 + k0 + ak);
        As[ak + 0][ar] = av.x; As[ak + 1][ar] = av.y;
        As[ak + 2][ar] = av.z; As[ak + 3][ar] = av.w;
        float4 bv = *(const float4*)(B + (size_t)(k0 + bk) * 256 + n0 + bn);
        *(float4*)&Bs[bk][bn] = bv;
        __syncthreads();
#pragma unroll
        for (int kk = 0; kk < 16; kk++) {
            float4 a = *(const float4*)&As[kk][ty << 2];
            float4 b = *(const float4*)&Bs[kk][tx << 2];
            acc[0][0] += a.x * b.x; acc[0][1] += a.x * b.y; acc[0][2] += a.x * b.z; acc[0][3] += a.x * b.w;
            acc[1][0] += a.y * b.x; acc[1][1] += a.y * b.y; acc[1][2] += a.y * b.z; acc[1][3] += a.y * b.w;
            acc[2][0] += a.z * b.x; acc[2][1] += a.z * b.y; acc[2][2] += a.z * b.z; acc[2][3] += a.z * b.w;
            acc[3][0] += a.w * b.x; acc[3][1] += a.w * b.y; acc[3][2] += a.w * b.z; acc[3][3] += a.w * b.w;
        }
        __syncthreads();
    }
#pragma unroll
    for (int i = 0; i < 4; i++) {
        int row = m0 + (ty << 2) + i;
        if (row < M) {
            size_t o = (size_t)row * 256 + n0 + (tx << 2);
            float4 v = make_float4(acc[i][0], acc[i][1], acc[i][2], acc[i][3]);
            *(float4*)(C + o) = v;
            ushort4 vb;
            vb.x = f2bf(v.x); vb.y = f2bf(v.y); vb.z = f2bf(v.z); vb.w = f2bf(v.w);
            *(ushort4*)(Cb + o) = vb;
        }
    }
}

// ---------------------------------------------------------------- plain gemm kernel (layer 2)
__global__ __launch_bounds__(256) void gemm_kernel(const float* __restrict__ A,
                                                   const float* __restrict__ B,
                                                   float* __restrict__ C,
                                                   unsigned short* __restrict__ Cb,
                                                   int M) {
    gemm_body(A, B, C, Cb, M, blockIdx.x, blockIdx.y);
}

// ---------------------------------------------------------------- fused fill + gemm1
// gemm blocks first (compute-bound), fill blocks after (write/latency-bound):
// complementary pipes co-schedule. CSR record = int2{src, bits(w)}.
__global__ __launch_bounds__(256) void fill_gemm_kernel(const int* __restrict__ src,
                                                        const int* __restrict__ dst,
                                                        const float* __restrict__ dinv,
                                                        int* __restrict__ cursor,
                                                        int2* __restrict__ csr,
                                                        const float* __restrict__ A,
                                                        const float* __restrict__ B,
                                                        float* __restrict__ C,
                                                        unsigned short* __restrict__ Cb) {
    if (blockIdx.x < GEMM_BLK) {
        gemm_body(A, B, C, Cb, NP, blockIdx.x >> 2, blockIdx.x & 3);
        return;
    }
    int e = (blockIdx.x - GEMM_BLK) * 256 + threadIdx.x;
    if (e >= ESG) return;
    int s = src[e], d = dst[e];
    int pos = atomicAdd(&cursor[d], 1);
    int2 rec;
    rec.x = s;
    rec.y = __float_as_int(dinv[s] * dinv[d]);
    csr[pos] = rec;
}

// ---------------------------------------------------------------- SpMM, monolithic, bf16 gather
// Block = one dst row, 256 threads = one channel each. Cooperative 256-edge
// LDS stage, then each thread makes unrolled independent bf16 gathers.
// Self-loop / bias / residual read fp32; optional fp32 and bf16 outputs.
__global__ __launch_bounds__(256) void spmm_kernel(const unsigned short* __restrict__ hwbf,
                                                   const float* __restrict__ hw,
                                                   const int* __restrict__ row_ptr,
                                                   const int2* __restrict__ csr,
                                                   const float* __restrict__ dinv,
                                                   const float* __restrict__ bias,
                                                   const float* __restrict__ residual,
                                                   float* __restrict__ outf,
                                                   unsigned short* __restrict__ outbf,
                                                   int do_relu) {
    int row = blockIdx.x;
    int ch  = threadIdx.x;
    int lo = row_ptr[row], hi = row_ptr[row + 1];
    __shared__ int2 s_rec[256];
    float acc = 0.f;
    for (int base = lo; base < hi; base += 256) {   // trip count uniform per block
        int i = base + ch;
        if (i < hi) s_rec[ch] = csr[i];
        __syncthreads();
        int cnt = min(256, hi - base);
#pragma unroll 4
        for (int j = 0; j < cnt; j++) {
            int2 r = s_rec[j];
            acc += __int_as_float(r.y) * bf2f(hwbf[(size_t)r.x * 256 + ch]);
        }
        __syncthreads();
    }
    float dv = dinv[row];
    size_t o = (size_t)row * 256 + ch;
    acc += hw[o] * dv * dv + bias[ch];
    if (residual) acc += residual[o];
    if (do_relu) acc = fmaxf(acc, 0.f);
    if (outf)  outf[o] = acc;
    if (outbf) outbf[o] = f2bf(acc);
}

// ---------------------------------------------------------------- pooling, bf16 gather
// grid = (ND, PSPLIT): block (d, part) sums its share of drug d's node list
// (LDS-staged, unrolled gathers), atomically accumulates; fin divides.
__global__ __launch_bounds__(256) void pool_kernel(const unsigned short* __restrict__ h2bf,
                                                   const int* __restrict__ sg_nodes,
                                                   const int* __restrict__ sg_idx,
                                                   float* __restrict__ drug_emb) {
    int d    = blockIdx.x;
    int part = blockIdx.y;
    int ch   = threadIdx.x;
    __shared__ int s_nodes[256];
    int lo0 = lower_bound_dev(sg_idx, NSG, d);       // uniform across block
    int hi0 = lower_bound_dev(sg_idx, NSG, d + 1);
    int len = hi0 - lo0;
    int lo = lo0 + (int)(((long long)len * part) / PSPLIT);
    int hi = lo0 + (int)(((long long)len * (part + 1)) / PSPLIT);
    float acc = 0.f;
    for (int base = lo; base < hi; base += 256) {
        int i = base + ch;
        if (i < hi) s_nodes[ch] = sg_nodes[i];
        __syncthreads();
        int cnt = min(256, hi - base);
#pragma unroll 4
        for (int j = 0; j < cnt; j++) {
            acc += bf2f(h2bf[(size_t)s_nodes[j] * 256 + ch]);
        }
        __syncthreads();
    }
    atomicAdd(&drug_emb[(size_t)d * 256 + ch], acc);
}

__global__ __launch_bounds__(256) void pool_fin_kernel(const int* __restrict__ sg_idx,
                                                       float* __restrict__ drug_emb) {
    int d  = blockIdx.x;
    int ch = threadIdx.x;
    int lo = lower_bound_dev(sg_idx, NSG, d);
    int hi = lower_bound_dev(sg_idx, NSG, d + 1);
    float c = (float)max(hi - lo, 1);
    drug_emb[(size_t)d * 256 + ch] /= c;
}

// ---------------------------------------------------------------- dot head (wave per pair)
__global__ __launch_bounds__(256) void dot_kernel(const float* __restrict__ drug_emb,
                                                  const int* __restrict__ ddb,
                                                  float* __restrict__ out) {
    int wave = threadIdx.x >> 6;
    int lane = threadIdx.x & 63;
    int p = blockIdx.x * 4 + wave;
    if (p >= BDD) return;
    int a = ddb[p];
    int b = ddb[BDD + p];
    const float4* ea = (const float4*)(drug_emb + (size_t)a * 256);
    const float4* eb = (const float4*)(drug_emb + (size_t)b * 256);
    float4 va = ea[lane];
    float4 vb = eb[lane];
    float s = va.x * vb.x + va.y * vb.y + va.z * vb.z + va.w * vb.w;
#pragma unroll
    for (int off = 32; off > 0; off >>= 1) s += __shfl_down(s, off, 64);
    if (lane == 0) out[p] = s;
}

// ---------------------------------------------------------------- launcher
extern "C" void kernel_launch(void* const* d_in, const int* in_sizes, int n_in,
                              void* d_out, int out_size, void* d_ws, size_t ws_size,
                              hipStream_t stream) {
    const float* x        = (const float*)d_in[0];
    const int*   ddb      = (const int*)d_in[1];
    // d_in[2] edge_attr, d_in[3] edge_cell_lines: unused by reference
    const int*   sg_edge  = (const int*)d_in[4];   // [2, ESG]: src then dst
    const int*   sg_nodes = (const int*)d_in[5];
    const int*   sg_idx   = (const int*)d_in[6];
    const float* W1       = (const float*)d_in[7];
    const float* b1       = (const float*)d_in[8];
    const float* W2       = (const float*)d_in[9];
    const float* b2       = (const float*)d_in[10];
    float* out = (float*)d_out;

    char* ws = (char*)d_ws;
    size_t off = 0;
    auto alloc = [&](size_t bytes) -> void* {
        void* p = ws + off;
        off = (off + bytes + 255) & ~(size_t)255;
        return p;
    };
    int*   deg      = (int*)alloc(NP * sizeof(int));
    float* dinv     = (float*)alloc(NP * sizeof(float));
    int*   row_ptr  = (int*)alloc((NP + 1) * sizeof(int));
    int*   cursor   = (int*)alloc(NP * sizeof(int));
    int2*  csr      = (int2*)alloc((size_t)ESG * sizeof(int2));
    float* bufA     = (float*)alloc((size_t)NP * CHN * sizeof(float));            // hw1, then hw2
    unsigned short* bufAbf = (unsigned short*)alloc((size_t)NP * CHN * 2);        // bf16 twin
    float* h1       = (float*)alloc((size_t)NP * CHN * sizeof(float));
    unsigned short* h2bf   = (unsigned short*)alloc((size_t)NP * CHN * 2);
    float* drug_emb = (float*)alloc((size_t)ND * CHN * sizeof(float));

    const int* src = sg_edge;
    const int* dst = sg_edge + ESG;

    hipMemsetAsync(deg, 0, NP * sizeof(int), stream);
    hipMemsetAsync(drug_emb, 0, (size_t)ND * CHN * sizeof(float), stream);
    deg_kernel<<<(ESG + 255) / 256, 256, 0, stream>>>(dst, deg);
    dinv_kernel<<<(NP + 255) / 256, 256, 0, stream>>>(deg, dinv);
    scan_kernel<<<1, 256, 0, stream>>>(deg, row_ptr, cursor);

    // fused: CSR fill + gemm1 (bufA/bufAbf = x @ W1)
    fill_gemm_kernel<<<GEMM_BLK + FILL_BLK, 256, 0, stream>>>(src, dst, dinv, cursor,
                                                              csr, x, W1, bufA, bufAbf);
    // layer 1: h1 = relu(agg(bf16 gather) + self + b1)   [fp32 out only]
    spmm_kernel<<<NP, 256, 0, stream>>>(bufAbf, bufA, row_ptr, csr, dinv, b1,
                                        nullptr, h1, nullptr, 1);
    // layer 2: bufA/bufAbf = h1 @ W2 ; h2bf = agg + self + b2 + h1  [bf16 out only]
    gemm_kernel<<<dim3(GEMM_BX, 4), 256, 0, stream>>>(h1, W2, bufA, bufAbf, NP);
    spmm_kernel<<<NP, 256, 0, stream>>>(bufAbf, bufA, row_ptr, csr, dinv, b2,
                                        h1, nullptr, h2bf, 0);
    // scatter-mean pooling (bf16 gather, entry-split, atomic) + finalize
    pool_kernel<<<dim3(ND, PSPLIT), 256, 0, stream>>>(h2bf, sg_nodes, sg_idx, drug_emb);
    pool_fin_kernel<<<ND, 256, 0, stream>>>(sg_idx, drug_emb);
    // dot-product head
    dot_kernel<<<(BDD + 3) / 4, 256, 0, stream>>>(drug_emb, ddb, out);
}